// Round 8
// baseline (357.259 us; speedup 1.0000x reference)
//
#include <hip/hip_runtime.h>

#define N_RELS 16
#define N_BASES 8
#define HD 128
#define SCAN_B 1024
#define ROWS 16

typedef __attribute__((ext_vector_type(8))) short bf16x8;
typedef __attribute__((ext_vector_type(4))) float floatx4;
typedef __attribute__((ext_vector_type(2))) float floatx2;

__device__ __forceinline__ short bf16rn(float f) {
    union { float f; unsigned u; } v; v.f = f;
    unsigned u = v.u;
    unsigned r = (u + 0x7fffu + ((u >> 16) & 1u)) >> 16;
    return (short)r;
}

// packed f32x2 -> bf16x2 (RNE), gfx950 single instruction
__device__ __forceinline__ unsigned cvtpk_bf16(float lo, float hi) {
    unsigned r;
    asm("v_cvt_pk_bf16_f32 %0, %1, %2" : "=v"(r) : "v"(lo), "v"(hi));
    return r;
}

// ---------------- fused setup: pack h->bf16 | V->frags | (dst,et) histogram ----------------

__global__ void setup_fused(const float* __restrict__ h, unsigned* __restrict__ hb, int n4,
                            const float* __restrict__ V1, const float* __restrict__ V2,
                            short* __restrict__ Vf,
                            const int* __restrict__ dst, const int* __restrict__ et,
                            int E, int* __restrict__ cnt,
                            int packBlocks, int vBlocks) {
    int blk = blockIdx.x;
    if (blk < packBlocks) {
        int i = blk * blockDim.x + threadIdx.x;
        if (i < n4) {
            float4 v = ((const float4*)h)[i];
            uint2 o;
            o.x = ((unsigned)(unsigned short)bf16rn(v.y) << 16) | (unsigned short)bf16rn(v.x);
            o.y = ((unsigned)(unsigned short)bf16rn(v.w) << 16) | (unsigned short)bf16rn(v.z);
            ((uint2*)hb)[i] = o;
        }
        return;
    }
    blk -= packBlocks;
    if (blk < vBlocks) {
        // frag: lane holds B[n=lane&15][k=(lane>>4)*8+j]; idx = ((kk*8+t)*64+lane)*8+j
        const float* V = ((blk & 8) ? V2 : V1) + (size_t)(blk & 7) * 16384;
        size_t obase = (size_t)blk * 16384;
        for (int e = threadIdx.x; e < 16384; e += blockDim.x) {
            float w = V[e];
            int k = e >> 7, n = e & 127;
            int kk = k >> 5, q = (k >> 3) & 3, j = k & 7;
            int lane = q * 16 + (n & 15);
            int idx = ((kk * 8 + (n >> 4)) * 64 + lane) * 8 + j;
            Vf[obase + idx] = bf16rn(w);
        }
        return;
    }
    blk -= vBlocks;
    int i = blk * blockDim.x + threadIdx.x;
    if (i < E) atomicAdd(&cnt[dst[i] * N_RELS + et[i]], 1);
}

// ---------------- counting-sort scan over N*16 buckets (2-level) ----------------

__global__ void scan_partial(const int* __restrict__ cnt, int N,
                             int* __restrict__ excl, int* __restrict__ bsum) {
    __shared__ int s[SCAN_B];
    int t = threadIdx.x, i = blockIdx.x * SCAN_B + t;
    int v = (i < N) ? cnt[i] : 0;
    s[t] = v; __syncthreads();
    for (int o = 1; o < SCAN_B; o <<= 1) {
        int x = (t >= o) ? s[t - o] : 0;
        __syncthreads();
        s[t] += x;
        __syncthreads();
    }
    if (i < N) excl[i] = s[t] - v;
    if (t == SCAN_B - 1) bsum[blockIdx.x] = s[t];
}

// add second-level exclusive block prefix; init cursor; sentinel
__global__ void fixup16(int* __restrict__ excl, const int* __restrict__ bsumE,
                        int NK, int E, int* __restrict__ cursor) {
    int i = blockIdx.x * blockDim.x + threadIdx.x;
    if (i < NK) {
        int v = excl[i] + bsumE[i >> 10];
        excl[i] = v;
        cursor[i] = v;
    }
    if (i == 0) excl[NK] = E;
}

// scatter into (dst,et)-sorted order; pack (etype, src) into one int: src < 65536
__global__ void scatter_dst(const int* __restrict__ dst, const int* __restrict__ src,
                            const int* __restrict__ et, const float* __restrict__ norm,
                            int E, int* __restrict__ cursor, int2* __restrict__ edata) {
    int i = blockIdx.x * blockDim.x + threadIdx.x;
    if (i >= E) return;
    int p = atomicAdd(&cursor[dst[i] * N_RELS + et[i]], 1);
    edata[p] = make_int2((et[i] << 16) | src[i], __float_as_int(norm[i]));
}

// ---------------- fused per-tile RGCN layer (relation-space) ----------------
// Block = 16 dst rows, 512 threads (8 waves). Edges sorted by (dst,et) -> per row the
// relations form contiguous runs. Phase A (half-wave per row, lane l32 = dwords
// 2*l32..+1 of the 256B h-row): accumulate only the RUN sum S (4 floats/lane,
// S += h[src]*nv, one pk_fma per dword -- no basis loop per edge); on run boundary
// (et changes or row ends) cvt_pk S->bf16 and ds_write into the 16-relation LDS tile
// Z'[et]. Tiny registers (~40 live) -> no AGPR split / spills (rounds 4-6 disease).
// Drain-free period-6 rotation: edata 4 trips ahead (6 slots), gathers 2 ahead (3
// slots); every wait is a counted vmcnt. FOLD (per-thread, own slots, no barrier):
// Zb[b] = sum_r coef[r,b] * Z'[r], written in-place into rel-slots 0..7.
// Phase B: Zb(16x1024) @ V(1024x128) basis GEMM; B-frags from L2-resident Vf;
// wave = t-tile tt, 32 MFMA. mode 0: bf16(relu(+bias)); mode 1: fp32(+bias).

__global__ __launch_bounds__(512, 4) void rgcn_tile(
    const unsigned* __restrict__ hb, const int2* __restrict__ edata,
    const int* __restrict__ rp16, const float* __restrict__ coef,
    const short* __restrict__ Vf, const float* __restrict__ bias,
    void* __restrict__ outp, int N, int E, int mode) {
    __shared__ __align__(16) unsigned Zs[N_RELS][4][4][ROWS + 1][4];   // 69.6 KB
    __shared__ __align__(16) floatx2 cofs2[N_RELS][N_BASES];           // 1 KB {c,c}

    const int tid = threadIdx.x;
    const int wave = tid >> 6, lane = tid & 63;
    const int l32 = tid & 31;
    const int nb0 = blockIdx.x * ROWS;

    // zero Z' (4352 uint4)
    for (int i = tid; i < 4352; i += 512) ((uint4*)Zs)[i] = make_uint4(0, 0, 0, 0);
    if (tid < N_RELS * N_BASES) {
        float c = coef[tid];
        floatx2 p; p.x = c; p.y = c;
        cofs2[tid >> 3][tid & 7] = p;
    }
    __syncthreads();

    // half-wave id = local row 0..15
    const int r = tid >> 5;
    const int node = nb0 + r;
    const int cn = (node < N) ? node : (N - 1);
    const int s = rp16[cn * N_RELS];
    const int len = (node < N) ? (rp16[cn * N_RELS + N_RELS] - s) : 0;

    int mx = max(len, __shfl_xor(len, 32, 64));
    const int nG = __builtin_amdgcn_readfirstlane(mx);

    floatx2 a0 = {}, a1 = {};
    const uint2* hbp = (const uint2*)hb;
    // lane's flush base: dword d0=2*l32 -> kk=l32>>3, q=(l32>>1)&3, slot=(l32&1)*2
    unsigned* const flushp = &Zs[0][l32 >> 3][(l32 >> 1) & 3][r][(l32 & 1) * 2];
    const int ET_STRIDE = 4 * 4 * (ROWS + 1) * 4;   // 1088 unsigneds

    auto edix = [&](int j) { int ix = s + j; return (ix > E - 1) ? (E - 1) : ix; };
    auto gath = [&](int2 m) { return hbp[(size_t)(m.x & 0xffff) * 32 + l32]; };
    auto proc = [&](int2 m, int2 mn, uint2 g, int j) {
        const bool inr = j < len;
        float nv = inr ? __int_as_float(m.y) : 0.f;
        floatx2 nvp; nvp.x = nv; nvp.y = nv;
        floatx2 v0, v1;
        v0.x = __uint_as_float(g.x << 16); v0.y = __uint_as_float(g.x & 0xffff0000u);
        v1.x = __uint_as_float(g.y << 16); v1.y = __uint_as_float(g.y & 0xffff0000u);
        a0 = v0 * nvp + a0;                         // v_pk_fma_f32
        a1 = v1 * nvp + a1;
        int etc = m.x >> 16;
        int etn = (j + 1 < len) ? (mn.x >> 16) : -1;
        if (inr && etn != etc) {                    // run boundary: flush S -> Z'[et]
            uint2 w;
            w.x = cvtpk_bf16(a0.x, a0.y);
            w.y = cvtpk_bf16(a1.x, a1.y);
            *(uint2*)(flushp + etc * ET_STRIDE) = w;
            a0.x = 0.f; a0.y = 0.f; a1.x = 0.f; a1.y = 0.f;
        }
    };

    // prologue: 6 edata slots, 2 gathers in flight
    int2 mA = edata[edix(0)], mB = edata[edix(1)], mC = edata[edix(2)];
    int2 mD = edata[edix(3)], mE = edata[edix(4)], mF = edata[edix(5)];
    uint2 gA = gath(mA), gB = gath(mB), gC;

    for (int k = 0; k < nG; k += 6) {
        gC = gath(mC); proc(mA, mB, gA, k + 0); mA = edata[edix(k + 6)];
        gA = gath(mD); proc(mB, mC, gB, k + 1); mB = edata[edix(k + 7)];
        gB = gath(mE); proc(mC, mD, gC, k + 2); mC = edata[edix(k + 8)];
        gC = gath(mF); proc(mD, mE, gA, k + 3); mD = edata[edix(k + 9)];
        gA = gath(mA); proc(mE, mF, gB, k + 4); mE = edata[edix(k + 10)];
        gB = gath(mB); proc(mF, mA, gC, k + 5); mF = edata[edix(k + 11)];
    }
    // last in-range edge flushed inside loop (etn=-1 at j+1==len); len==0 rows stay zero

    // ---- fold: Zb[b] = sum_r coef[r,b] * Z'[r], own slots only (no barrier needed)
    {
        floatx2 o0[N_BASES] = {}, o1[N_BASES] = {};
#pragma unroll
        for (int rr = 0; rr < N_RELS; rr++) {
            uint2 w = *(uint2*)(flushp + rr * ET_STRIDE);
            floatx2 v0, v1;
            v0.x = __uint_as_float(w.x << 16); v0.y = __uint_as_float(w.x & 0xffff0000u);
            v1.x = __uint_as_float(w.y << 16); v1.y = __uint_as_float(w.y & 0xffff0000u);
#pragma unroll
            for (int b = 0; b < N_BASES; b++) {
                floatx2 cw = cofs2[rr][b];
                o0[b] = v0 * cw + o0[b];
                o1[b] = v1 * cw + o1[b];
            }
        }
#pragma unroll
        for (int b = 0; b < N_BASES; b++) {
            uint2 w;
            w.x = cvtpk_bf16(o0[b].x, o0[b].y);
            w.y = cvtpk_bf16(o1[b].x, o1[b].y);
            *(uint2*)(flushp + b * ET_STRIDE) = w;
        }
    }
    __syncthreads();

    // ---- phase B: wave owns t-tile tt=wave, single 16-row m-tile (reads rel-slots 0..7 = Zb)
    const int q = lane >> 4, cc = lane & 15;
    const int tt = wave;
    floatx4 ac = {};

#pragma unroll 2
    for (int b = 0; b < N_BASES; b++) {
#pragma unroll
        for (int kk = 0; kk < 4; kk++) {
            bf16x8 a = *(const bf16x8*)&Zs[b][kk][q][cc][0];
            bf16x8 B = *(const bf16x8*)(Vf + (size_t)b * 16384 +
                                        ((size_t)(kk * 8 + tt) * 64 + lane) * 8);
            ac = __builtin_amdgcn_mfma_f32_16x16x32_bf16(a, B, ac, 0, 0, 0);
        }
    }

    // ---- epilogue: C/D layout col = tt*16+cc, row = q*4+i
    float bv = bias[tt * 16 + cc];
    if (mode == 0) {
        unsigned short* o = (unsigned short*)outp;
#pragma unroll
        for (int i = 0; i < 4; i++) {
            int nd = nb0 + q * 4 + i;
            if (nd < N) {
                float v = fmaxf(ac[i] + bv, 0.f);
                o[(size_t)nd * HD + tt * 16 + cc] = (unsigned short)bf16rn(v);
            }
        }
    } else {
        float* o = (float*)outp;
#pragma unroll
        for (int i = 0; i < 4; i++) {
            int nd = nb0 + q * 4 + i;
            if (nd < N) o[(size_t)nd * HD + tt * 16 + cc] = ac[i] + bv;
        }
    }
}

// ---------------- launch ----------------

extern "C" void kernel_launch(void* const* d_in, const int* in_sizes, int n_in,
                              void* d_out, int out_size, void* d_ws, size_t ws_size,
                              hipStream_t stream) {
    const float* h     = (const float*)d_in[0];
    const float* norm  = (const float*)d_in[1];
    const int*   src   = (const int*)d_in[2];
    const int*   dst   = (const int*)d_in[3];
    const int*   etype = (const int*)d_in[4];
    const float* V1    = (const float*)d_in[5];
    const float* coef1 = (const float*)d_in[6];
    const float* bias1 = (const float*)d_in[7];
    const float* V2    = (const float*)d_in[8];
    const float* coef2 = (const float*)d_in[9];
    const float* bias2 = (const float*)d_in[10];
    const int N = in_sizes[0] / HD;   // 50000
    const int E = in_sizes[2];        // 640000
    const int NK = N * N_RELS;        // 800000
    float* out = (float*)d_out;
    (void)n_in; (void)out_size; (void)ws_size;

    char* ws = (char*)d_ws;
    size_t off = 0;
    auto alloc = [&](size_t bytes) {
        void* p = ws + off;
        off += (bytes + 255) & ~(size_t)255;
        return p;
    };
    short*    Vf      = (short*)alloc((size_t)16 * 16384 * sizeof(short));   // 512 KB
    unsigned* hb      = (unsigned*)alloc((size_t)N * 64 * sizeof(unsigned)); // 12.8 MB
    unsigned* h1b     = (unsigned*)alloc((size_t)N * 64 * sizeof(unsigned)); // 12.8 MB
    int2*     edata   = (int2*)alloc((size_t)E * sizeof(int2));
    int*      cnt16   = (int*)alloc((size_t)NK * sizeof(int));               // 3.2 MB
    int*      excl16  = (int*)alloc((size_t)(NK + 1) * sizeof(int));
    int*      cursor  = (int*)alloc((size_t)NK * sizeof(int));
    int*      bsum    = (int*)alloc(1024 * sizeof(int));
    int*      bsumE   = (int*)alloc(1024 * sizeof(int));
    int*      dummy   = (int*)alloc(16 * sizeof(int));

    const int nb16 = (NK + SCAN_B - 1) / SCAN_B;              // 782
    const int packBlocks = (N * 32 + 255) / 256;              // 6250 (float4 pack)
    const int vBlocks = 16;
    const int histBlocks = (E + 255) / 256;                   // 2500

    hipMemsetAsync(cnt16, 0, (size_t)NK * sizeof(int), stream);
    setup_fused<<<packBlocks + vBlocks + histBlocks, 256, 0, stream>>>(
        h, hb, N * 32, V1, V2, Vf, dst, etype, E, cnt16, packBlocks, vBlocks);
    scan_partial<<<nb16, SCAN_B, 0, stream>>>(cnt16, NK, excl16, bsum);
    scan_partial<<<1, SCAN_B, 0, stream>>>(bsum, nb16, bsumE, dummy);
    fixup16<<<(NK + 255) / 256, 256, 0, stream>>>(excl16, bsumE, NK, E, cursor);
    scatter_dst<<<(E + 255) / 256, 256, 0, stream>>>(dst, src, etype, norm, E, cursor, edata);

    const int tiles = (N + ROWS - 1) / ROWS;   // 3125

    // layer 1: h1b = bf16(relu(bias1 + Z @ V1))
    rgcn_tile<<<tiles, 512, 0, stream>>>(hb, edata, excl16, coef1, Vf, bias1, h1b, N, E, 0);
    // layer 2: out = bias2 + Z(h1b) @ V2
    rgcn_tile<<<tiles, 512, 0, stream>>>(h1b, edata, excl16, coef2, Vf + (size_t)8 * 16384,
                                         bias2, out, N, E, 1);
}